// Round 17
// baseline (134.781 us; speedup 1.0000x reference)
//
#include <hip/hip_runtime.h>
#include <hip/hip_bf16.h>

// Shapes fixed by setup_inputs(): B=2, C=128, H=256, W=448, stride=1.
#define BB 2
#define CC 128
#define HH 256
#define WW 448
#define KK 49
#define HWSZ (HH * WW)
#define PW 456  // padded width of wt: px = x+4, x in [-4, 452)

#define WT_BYTES ((size_t)BB * HH * PW * CC * 2)      // 59,768,832
#define TWT_BYTES ((size_t)BB * HH * WW * CC * 2)     // 58,720,256
#define WS_NEED (WT_BYTES + TWT_BYTES)

typedef __attribute__((ext_vector_type(8))) short bf16x8;
typedef __attribute__((ext_vector_type(4))) float f32x4;
typedef __attribute__((ext_vector_type(8))) unsigned short u16x8;

static __device__ __forceinline__ short f2bf(float v) {
  __hip_bfloat16 h = __float2bfloat16(v);
  return *reinterpret_cast<short*>(&h);
}
static __device__ __forceinline__ float bf2f(unsigned short u) {
  unsigned int x = ((unsigned int)u) << 16;
  return __uint_as_float(x);
}

typedef const __attribute__((address_space(1))) unsigned int* as1_u32p;
typedef __attribute__((address_space(3))) unsigned int* as3_u32p;
static __device__ __forceinline__ void gload_lds16(const void* g, void* l) {
  __builtin_amdgcn_global_load_lds((as1_u32p)g, (as3_u32p)l, 16, 0, 0);
}

// ---------------- Kernel 0 (fallback path only): zero wt x-pad borders ------
__global__ __launch_bounds__(256) void border_kernel(__hip_bfloat16* wt) {
  int i = blockIdx.x * 256 + threadIdx.x;  // 65536
  int by = i >> 7;
  int r = i & 127;
  int ps = r >> 4;
  int c16 = r & 15;
  int px = (ps < 4) ? ps : (448 + ps);
  u16x8 z = {0, 0, 0, 0, 0, 0, 0, 0};
  *(u16x8*)((char*)wt + ((size_t)((size_t)by * PW + px) * CC + c16 * 8) * 2) = z;
}

// ---------------- Kernel T: transpose tenTwo [c][p] f32 -> two_t [p][c] bf16
// Blocks 0..255 additionally zero wt's x-pad borders.
__global__ __launch_bounds__(256) void transpose_kernel(
    const float* __restrict__ two, __hip_bfloat16* __restrict__ two_t,
    __hip_bfloat16* __restrict__ wt) {
  __shared__ float lds[128 * 33];
  int bid = blockIdx.x;            // BB * 3584 = 7168
  if (bid < 256) {                 // folded border zeroing (1 MB total)
    int i = bid * 256 + threadIdx.x;
    int by = i >> 7;
    int r = i & 127;
    int ps = r >> 4;
    int c16 = r & 15;
    int px = (ps < 4) ? ps : (448 + ps);
    u16x8 z = {0, 0, 0, 0, 0, 0, 0, 0};
    *(u16x8*)((char*)wt + ((size_t)((size_t)by * PW + px) * CC + c16 * 8) * 2) =
        z;
  }
  int b = bid / (HWSZ / 32);
  int tile = bid - b * (HWSZ / 32);
  int P0 = tile * 32;

  const float* src = two + (size_t)b * CC * HWSZ + P0;
  int t = threadIdx.x;
  int bc = t >> 3;   // 0..31
  int f = t & 7;     // 0..7
#pragma unroll
  for (int k = 0; k < 4; ++k) {
    int c = bc + k * 32;
    float4 v = *(const float4*)(src + (size_t)c * HWSZ + f * 4);
    float* d = &lds[c * 33 + f * 4];
    d[0] = v.x; d[1] = v.y; d[2] = v.z; d[3] = v.w;
  }
  __syncthreads();

  int q = t & 7;     // c-chunk of 16
  int pl = t >> 3;   // 0..31 pixel
  int cs = q * 16;
  u16x8 pk0, pk1;
#pragma unroll
  for (int j = 0; j < 8; ++j)
    pk0[j] = (unsigned short)f2bf(lds[(cs + j) * 33 + pl]);
#pragma unroll
  for (int j = 0; j < 8; ++j)
    pk1[j] = (unsigned short)f2bf(lds[(cs + 8 + j) * 33 + pl]);
  char* dst = (char*)two_t + ((size_t)((size_t)b * HWSZ + P0 + pl) * CC + cs) * 2;
  *(u16x8*)dst = pk0;
  *(u16x8*)(dst + 16) = pk1;
}

// ---------------- Kernel 1 (fast): gather from two_t [p][c] bf16 -----------
__global__ __launch_bounds__(1024) void warp_fast(
    const __hip_bfloat16* __restrict__ two_t, const float* __restrict__ flow,
    __hip_bfloat16* __restrict__ wt) {
  int bid = blockIdx.x;                    // 3584 = 8 * 448
  int wg = (bid & 7) * 448 + (bid >> 3);   // XCD-chunked, bijective
  int b = wg / 1792;
  int rem = wg - b * 1792;
  int y = rem / 7;
  int seg = rem - y * 7;
  int pg = threadIdx.x >> 4;  // 0..63 pixel group
  int cw = threadIdx.x & 15;  // 16B channel chunk
  int x = seg * 64 + pg;

  float fx = flow[(size_t)(b * 2 + 0) * HWSZ + y * WW + x] * 2.5f;
  float fy = flow[(size_t)(b * 2 + 1) * HWSZ + y * WW + x] * 2.5f;
  float px = (float)x + fx;
  float py = (float)y + fy;
  float x0f = floorf(px), y0f = floorf(py);
  int x0 = (int)x0f, y0 = (int)y0f;
  int x1 = x0 + 1, y1 = y0 + 1;
  float wx1 = px - x0f, wx0 = 1.0f - wx1;
  float wy1 = py - y0f, wy0 = 1.0f - wy1;
  bool vx0 = (x0 >= 0) && (x0 < WW);
  bool vx1 = (x1 >= 0) && (x1 < WW);
  bool vy0 = (y0 >= 0) && (y0 < HH);
  bool vy1 = (y1 >= 0) && (y1 < HH);
  float w00 = (vx0 && vy0) ? wx0 * wy0 : 0.0f;
  float w01 = (vx1 && vy0) ? wx1 * wy0 : 0.0f;
  float w10 = (vx0 && vy1) ? wx0 * wy1 : 0.0f;
  float w11 = (vx1 && vy1) ? wx1 * wy1 : 0.0f;
  int cx0 = min(max(x0, 0), WW - 1);
  int cx1 = min(max(x1, 0), WW - 1);
  int cy0 = min(max(y0, 0), HH - 1);
  int cy1 = min(max(y1, 0), HH - 1);

  const char* tb = (const char*)two_t + (size_t)b * HWSZ * (CC * 2);
  u16x8 a = *(const u16x8*)(tb + ((size_t)cy0 * WW + cx0) * 256 + cw * 16);
  u16x8 bb_ = *(const u16x8*)(tb + ((size_t)cy0 * WW + cx1) * 256 + cw * 16);
  u16x8 c = *(const u16x8*)(tb + ((size_t)cy1 * WW + cx0) * 256 + cw * 16);
  u16x8 d = *(const u16x8*)(tb + ((size_t)cy1 * WW + cx1) * 256 + cw * 16);

  u16x8 pk;
#pragma unroll
  for (int e = 0; e < 8; ++e) {
    float v = w00 * bf2f((unsigned short)a[e]) +
              w01 * bf2f((unsigned short)bb_[e]) +
              w10 * bf2f((unsigned short)c[e]) +
              w11 * bf2f((unsigned short)d[e]);
    pk[e] = (unsigned short)f2bf(v);
  }
  *(u16x8*)((char*)wt + ((size_t)(b * HH + y) * PW + x + 4) * (CC * 2) +
            cw * 16) = pk;
}

// ---------------- Kernel 1 (fallback): gather f32 planes directly -----------
__global__ __launch_bounds__(256) void warp_fallback(
    const float* __restrict__ two, const float* __restrict__ flow,
    __hip_bfloat16* __restrict__ wt) {
  int idx = blockIdx.x * 256 + threadIdx.x;
  if (idx >= BB * HWSZ) return;
  int x = idx % WW;
  int y = (idx / WW) % HH;
  int b = idx / HWSZ;

  float fx = flow[(b * 2 + 0) * HWSZ + y * WW + x] * 2.5f;
  float fy = flow[(b * 2 + 1) * HWSZ + y * WW + x] * 2.5f;
  float px = (float)x + fx;
  float py = (float)y + fy;
  float x0f = floorf(px), y0f = floorf(py);
  int x0 = (int)x0f, y0 = (int)y0f;
  int x1 = x0 + 1, y1 = y0 + 1;
  float wx1 = px - x0f, wx0 = 1.0f - wx1;
  float wy1 = py - y0f, wy0 = 1.0f - wy1;
  bool vx0 = (x0 >= 0) && (x0 < WW);
  bool vx1 = (x1 >= 0) && (x1 < WW);
  bool vy0 = (y0 >= 0) && (y0 < HH);
  bool vy1 = (y1 >= 0) && (y1 < HH);
  float w00 = (vx0 && vy0) ? wx0 * wy0 : 0.0f;
  float w01 = (vx1 && vy0) ? wx1 * wy0 : 0.0f;
  float w10 = (vx0 && vy1) ? wx0 * wy1 : 0.0f;
  float w11 = (vx1 && vy1) ? wx1 * wy1 : 0.0f;
  int cx0 = min(max(x0, 0), WW - 1);
  int cx1 = min(max(x1, 0), WW - 1);
  int cy0 = min(max(y0, 0), HH - 1);
  int cy1 = min(max(y1, 0), HH - 1);
  int o00 = cy0 * WW + cx0;
  int o01 = cy0 * WW + cx1;
  int o10 = cy1 * WW + cx0;
  int o11 = cy1 * WW + cx1;

  const float* p = two + (size_t)b * CC * HWSZ;
  char* wo = (char*)wt + ((size_t)((size_t)(b * HH + y) * PW) + x + 4) * CC * 2;
#pragma unroll 4
  for (int j = 0; j < 16; ++j) {
    u16x8 pk;
#pragma unroll
    for (int jj = 0; jj < 8; ++jj) {
      int c = j * 8 + jj;
      const float* pc = p + (size_t)c * HWSZ;
      float v = w00 * pc[o00] + w01 * pc[o01] + w10 * pc[o10] + w11 * pc[o11];
      pk[jj] = (unsigned short)f2bf(v);
    }
    *(u16x8*)(wo + j * 16) = pk;
  }
}

// ---------------- Kernel 2: correlation via MFMA, 16-row blocks -------------
// 1024 thr / 16 waves; wave w owns row ybase+w. C-split halves through one
// 62KB buffer (stage h0 -> compute -> stage h1 -> compute). vs R16: same
// phase count per block but 2x work -> half the barrier walls per output;
// staging y-dup 22/16=1.375 (was 1.75). 896 blocks, XCD-chunked.
#define YTB 16
#define NROWS 22                 // YTB + 6
#define NPOS 22
#define HROWCH (NPOS * 8)        // 176 16B-chunks per row (64-ch half)
#define HCHUNKS (NROWS * HROWCH) // 3872 chunks = 61,952 B

__global__ __launch_bounds__(1024, 2) void corr_kernel(
    const float* __restrict__ one, const __hip_bfloat16* __restrict__ wt,
    float* __restrict__ out) {
  __shared__ uint4 ldsb[HCHUNKS];

  int bid = blockIdx.x;                    // 896 = 8 * 112
  int wg = (bid & 7) * 112 + (bid >> 3);   // XCD-chunked, bijective
  int b = wg / 448;
  int rem = wg - b * 448;
  int xt = rem >> 4;   // 0..27
  int yt = rem & 15;   // 0..15
  int ybase = yt * YTB;
  int X0 = xt * 16;
  int tid = threadIdx.x;
  int w = tid >> 6;   // wave 0..15
  int l = tid & 63;
  int lp = l & 15;
  int lg = l >> 4;
  int y = ybase + w;

  const char* wbase =
      (const char*)wt + (((size_t)(b * HH)) * PW + X0 + 1) * (CC * 2);
  bool interior = (ybase >= 3) && (ybase + NROWS - 3 <= HH);

// Stage half H (channels H*64 .. H*64+63) into ldsb.
// Interior: gload_lds, linear dest, pre-swizzled source (cw ^= p&7).
// Edge: reg staging with zero fill, swizzled ds_write (same placement).
#define STAGE_HALF(H)                                                         \
  if (interior) {                                                             \
    _Pragma("unroll") for (int k = 0; k < 4; ++k) {                           \
      int ci = tid + k * 1024;                                                \
      if (ci < HCHUNKS) {                                                     \
        int row = ci / HROWCH;                                                \
        int r2 = ci - row * HROWCH;                                           \
        int p = r2 >> 3;                                                      \
        int cw = r2 & 7;                                                      \
        int yy = ybase - 3 + row;                                             \
        const char* g = wbase + (size_t)yy * (PW * CC * 2) + p * 256 +        \
                        (H)*128 + (cw ^ (p & 7)) * 16;                        \
        gload_lds16(g, (char*)ldsb + (size_t)(k * 1024 + (tid & ~63)) * 16);  \
      }                                                                       \
    }                                                                         \
  } else {                                                                    \
    _Pragma("unroll") for (int k = 0; k < 4; ++k) {                           \
      int ci = tid + k * 1024;                                                \
      if (ci < HCHUNKS) {                                                     \
        int row = ci / HROWCH;                                                \
        int r2 = ci - row * HROWCH;                                           \
        int p = r2 >> 3;                                                      \
        int cw = r2 & 7;                                                      \
        int yy = ybase - 3 + row;                                             \
        uint4 v = {0, 0, 0, 0};                                               \
        if (yy >= 0 && yy < HH)                                               \
          v = *(const uint4*)(wbase + (size_t)yy * (PW * CC * 2) + p * 256 +  \
                              (H)*128 + cw * 16);                             \
        *(uint4*)((char*)ldsb + ((ci * 16) ^ ((p & 7) << 4))) = v;            \
      }                                                                       \
    }                                                                         \
  }

  // ---- stage half 0 + A fragments (all 128 ch; overlap in flight) ---------
  STAGE_HALF(0)
  const float* Abase = one + ((size_t)(b * CC) * HH + y) * WW + X0 + lp;
  bf16x8 afr[4];
#pragma unroll
  for (int t = 0; t < 4; ++t)
#pragma unroll
    for (int j = 0; j < 8; ++j)
      afr[t][j] = f2bf(Abase[(size_t)(t * 32 + lg * 8 + j) * HWSZ]);

  int p1 = (lp + 16 < 21) ? (lp + 16) : 21;
  int cs0[2], cs1[2];  // swizzled chunk-offset bytes, tl = 0,1 (same per half)
#pragma unroll
  for (int tl = 0; tl < 2; ++tl) {
    cs0[tl] = ((tl * 4 + lg) ^ (lp & 7)) << 4;
    cs1[tl] = ((tl * 4 + lg) ^ (p1 & 7)) << 4;
  }

  f32x4 acc[7][2] = {};

  __syncthreads();  // B1: half 0 staged (drains A loads too)

  // ---- compute half 0 (channels 0..63 -> afr[0],afr[1]) -------------------
#pragma unroll
  for (int dj = 0; dj < 7; ++dj) {
    int rl = w + dj;
    int b0 = (rl * NPOS + lp) << 7;
    int b1 = (rl * NPOS + p1) << 7;
#pragma unroll
    for (int tl = 0; tl < 2; ++tl) {
      bf16x8 v0 = *(const bf16x8*)((const char*)ldsb + (b0 + cs0[tl]));
      bf16x8 v1 = *(const bf16x8*)((const char*)ldsb + (b1 + cs1[tl]));
      acc[dj][0] = __builtin_amdgcn_mfma_f32_16x16x32_bf16(afr[tl], v0,
                                                           acc[dj][0], 0, 0, 0);
      acc[dj][1] = __builtin_amdgcn_mfma_f32_16x16x32_bf16(afr[tl], v1,
                                                           acc[dj][1], 0, 0, 0);
    }
  }

  __syncthreads();  // B2: all reads of half-0 buffer done
  STAGE_HALF(1)
  __syncthreads();  // B3: half 1 staged

  // ---- compute half 1 (channels 64..127 -> afr[2],afr[3]) -----------------
#pragma unroll
  for (int dj = 0; dj < 7; ++dj) {
    int rl = w + dj;
    int b0 = (rl * NPOS + lp) << 7;
    int b1 = (rl * NPOS + p1) << 7;
#pragma unroll
    for (int tl = 0; tl < 2; ++tl) {
      bf16x8 v0 = *(const bf16x8*)((const char*)ldsb + (b0 + cs0[tl]));
      bf16x8 v1 = *(const bf16x8*)((const char*)ldsb + (b1 + cs1[tl]));
      acc[dj][0] = __builtin_amdgcn_mfma_f32_16x16x32_bf16(afr[2 + tl], v0,
                                                           acc[dj][0], 0, 0, 0);
      acc[dj][1] = __builtin_amdgcn_mfma_f32_16x16x32_bf16(afr[2 + tl], v1,
                                                           acc[dj][1], 0, 0, 0);
    }
  }

  // ---- Epilogue: LDS transpose -> dense stores ----------------------------
  // D layout: col = lane&15 (+16*nt) = pos, row = 4*(lane>>4)+reg = x_local.
  __syncthreads();  // B4: reads done; reuse buffer as scratch (50 KB used)
  float* sc = (float*)ldsb;  // [49][16][16] f32, col-swizzled by +k (mod 16)
#pragma unroll
  for (int dj = 0; dj < 7; ++dj) {
#pragma unroll
    for (int nt = 0; nt < 2; ++nt) {
      int post = lp + 16 * nt;
#pragma unroll
      for (int r = 0; r < 4; ++r) {
        int xlc = 4 * lg + r;
        int di = post - xlc;
        if (di >= 0 && di <= 6) {
          int k = dj * 7 + di;
          sc[k * 256 + w * 16 + ((xlc + k) & 15)] = acc[dj][nt][r];
        }
      }
    }
  }
  __syncthreads();  // B5: sc written

  float* ob = out + (size_t)(b * KK) * HWSZ + (size_t)ybase * WW + X0;
#pragma unroll
  for (int i = 0; i < 13; ++i) {
    int e = tid + i * 1024;
    if (e < KK * 256) {
      int k = e >> 8;
      int yr = (e >> 4) & 15;
      int px = e & 15;
      float v = sc[k * 256 + yr * 16 + ((px + k) & 15)] * (1.0f / 128.0f);
      v = (v > 0.0f) ? v : 0.1f * v;
      ob[(size_t)k * HWSZ + yr * WW + px] = v;
    }
  }
#undef STAGE_HALF
}

// ---------------- launch ----------------------------------------------------
extern "C" void kernel_launch(void* const* d_in, const int* in_sizes, int n_in,
                              void* d_out, int out_size, void* d_ws,
                              size_t ws_size, hipStream_t stream) {
  const float* tenOne = (const float*)d_in[0];
  const float* tenTwo = (const float*)d_in[1];
  const float* tenFlow = (const float*)d_in[2];

  __hip_bfloat16* wt = (__hip_bfloat16*)d_ws;

  if (ws_size >= WS_NEED) {
    __hip_bfloat16* two_t = (__hip_bfloat16*)((char*)d_ws + WT_BYTES);
    transpose_kernel<<<BB * (HWSZ / 32), 256, 0, stream>>>(tenTwo, two_t, wt);
    warp_fast<<<3584, 1024, 0, stream>>>(two_t, tenFlow, wt);
  } else {
    border_kernel<<<256, 256, 0, stream>>>(wt);
    int blocks = (BB * HWSZ + 255) / 256;
    warp_fallback<<<blocks, 256, 0, stream>>>(tenTwo, tenFlow, wt);
  }
  corr_kernel<<<896, 1024, 0, stream>>>(tenOne, wt, (float*)d_out);
}

// Round 18
// 131.166 us; speedup vs baseline: 1.0276x; 1.0276x over previous
//
#include <hip/hip_runtime.h>
#include <hip/hip_bf16.h>

// Shapes fixed by setup_inputs(): B=2, C=128, H=256, W=448, stride=1.
#define BB 2
#define CC 128
#define HH 256
#define WW 448
#define KK 49
#define HWSZ (HH * WW)
#define PW 456  // padded width of wt: px = x+4, x in [-4, 452)

#define WT_BYTES ((size_t)BB * HH * PW * CC * 2)      // 59,768,832
#define TWT_BYTES ((size_t)BB * HH * WW * CC * 2)     // 58,720,256
#define WS_NEED (WT_BYTES + TWT_BYTES)

typedef __attribute__((ext_vector_type(8))) short bf16x8;
typedef __attribute__((ext_vector_type(4))) float f32x4;
typedef __attribute__((ext_vector_type(8))) unsigned short u16x8;

static __device__ __forceinline__ short f2bf(float v) {
  __hip_bfloat16 h = __float2bfloat16(v);
  return *reinterpret_cast<short*>(&h);
}
static __device__ __forceinline__ float bf2f(unsigned short u) {
  unsigned int x = ((unsigned int)u) << 16;
  return __uint_as_float(x);
}

typedef const __attribute__((address_space(1))) unsigned int* as1_u32p;
typedef __attribute__((address_space(3))) unsigned int* as3_u32p;
static __device__ __forceinline__ void gload_lds16(const void* g, void* l) {
  __builtin_amdgcn_global_load_lds((as1_u32p)g, (as3_u32p)l, 16, 0, 0);
}

// ---------------- Kernel 0 (fallback path only): zero wt x-pad borders ------
__global__ __launch_bounds__(256) void border_kernel(__hip_bfloat16* wt) {
  int i = blockIdx.x * 256 + threadIdx.x;  // 65536
  int by = i >> 7;
  int r = i & 127;
  int ps = r >> 4;
  int c16 = r & 15;
  int px = (ps < 4) ? ps : (448 + ps);
  u16x8 z = {0, 0, 0, 0, 0, 0, 0, 0};
  *(u16x8*)((char*)wt + ((size_t)((size_t)by * PW + px) * CC + c16 * 8) * 2) = z;
}

// ---------------- Kernel T: transpose tenTwo [c][p] f32 -> two_t [p][c] bf16
// Blocks 0..255 additionally zero wt's x-pad borders.
__global__ __launch_bounds__(256) void transpose_kernel(
    const float* __restrict__ two, __hip_bfloat16* __restrict__ two_t,
    __hip_bfloat16* __restrict__ wt) {
  __shared__ float lds[128 * 33];
  int bid = blockIdx.x;            // BB * 3584 = 7168
  if (bid < 256) {                 // folded border zeroing (1 MB total)
    int i = bid * 256 + threadIdx.x;
    int by = i >> 7;
    int r = i & 127;
    int ps = r >> 4;
    int c16 = r & 15;
    int px = (ps < 4) ? ps : (448 + ps);
    u16x8 z = {0, 0, 0, 0, 0, 0, 0, 0};
    *(u16x8*)((char*)wt + ((size_t)((size_t)by * PW + px) * CC + c16 * 8) * 2) =
        z;
  }
  int b = bid / (HWSZ / 32);
  int tile = bid - b * (HWSZ / 32);
  int P0 = tile * 32;

  const float* src = two + (size_t)b * CC * HWSZ + P0;
  int t = threadIdx.x;
  int bc = t >> 3;   // 0..31
  int f = t & 7;     // 0..7
#pragma unroll
  for (int k = 0; k < 4; ++k) {
    int c = bc + k * 32;
    float4 v = *(const float4*)(src + (size_t)c * HWSZ + f * 4);
    float* d = &lds[c * 33 + f * 4];
    d[0] = v.x; d[1] = v.y; d[2] = v.z; d[3] = v.w;
  }
  __syncthreads();

  int q = t & 7;     // c-chunk of 16
  int pl = t >> 3;   // 0..31 pixel
  int cs = q * 16;
  u16x8 pk0, pk1;
#pragma unroll
  for (int j = 0; j < 8; ++j)
    pk0[j] = (unsigned short)f2bf(lds[(cs + j) * 33 + pl]);
#pragma unroll
  for (int j = 0; j < 8; ++j)
    pk1[j] = (unsigned short)f2bf(lds[(cs + 8 + j) * 33 + pl]);
  char* dst = (char*)two_t + ((size_t)((size_t)b * HWSZ + P0 + pl) * CC + cs) * 2;
  *(u16x8*)dst = pk0;
  *(u16x8*)(dst + 16) = pk1;
}

// ---------------- Kernel 1 (fast): gather from two_t [p][c] bf16 -----------
__global__ __launch_bounds__(1024) void warp_fast(
    const __hip_bfloat16* __restrict__ two_t, const float* __restrict__ flow,
    __hip_bfloat16* __restrict__ wt) {
  int bid = blockIdx.x;                    // 3584 = 8 * 448
  int wg = (bid & 7) * 448 + (bid >> 3);   // XCD-chunked, bijective
  int b = wg / 1792;
  int rem = wg - b * 1792;
  int y = rem / 7;
  int seg = rem - y * 7;
  int pg = threadIdx.x >> 4;  // 0..63 pixel group
  int cw = threadIdx.x & 15;  // 16B channel chunk
  int x = seg * 64 + pg;

  float fx = flow[(size_t)(b * 2 + 0) * HWSZ + y * WW + x] * 2.5f;
  float fy = flow[(size_t)(b * 2 + 1) * HWSZ + y * WW + x] * 2.5f;
  float px = (float)x + fx;
  float py = (float)y + fy;
  float x0f = floorf(px), y0f = floorf(py);
  int x0 = (int)x0f, y0 = (int)y0f;
  int x1 = x0 + 1, y1 = y0 + 1;
  float wx1 = px - x0f, wx0 = 1.0f - wx1;
  float wy1 = py - y0f, wy0 = 1.0f - wy1;
  bool vx0 = (x0 >= 0) && (x0 < WW);
  bool vx1 = (x1 >= 0) && (x1 < WW);
  bool vy0 = (y0 >= 0) && (y0 < HH);
  bool vy1 = (y1 >= 0) && (y1 < HH);
  float w00 = (vx0 && vy0) ? wx0 * wy0 : 0.0f;
  float w01 = (vx1 && vy0) ? wx1 * wy0 : 0.0f;
  float w10 = (vx0 && vy1) ? wx0 * wy1 : 0.0f;
  float w11 = (vx1 && vy1) ? wx1 * wy1 : 0.0f;
  int cx0 = min(max(x0, 0), WW - 1);
  int cx1 = min(max(x1, 0), WW - 1);
  int cy0 = min(max(y0, 0), HH - 1);
  int cy1 = min(max(y1, 0), HH - 1);

  const char* tb = (const char*)two_t + (size_t)b * HWSZ * (CC * 2);
  u16x8 a = *(const u16x8*)(tb + ((size_t)cy0 * WW + cx0) * 256 + cw * 16);
  u16x8 bb_ = *(const u16x8*)(tb + ((size_t)cy0 * WW + cx1) * 256 + cw * 16);
  u16x8 c = *(const u16x8*)(tb + ((size_t)cy1 * WW + cx0) * 256 + cw * 16);
  u16x8 d = *(const u16x8*)(tb + ((size_t)cy1 * WW + cx1) * 256 + cw * 16);

  u16x8 pk;
#pragma unroll
  for (int e = 0; e < 8; ++e) {
    float v = w00 * bf2f((unsigned short)a[e]) +
              w01 * bf2f((unsigned short)bb_[e]) +
              w10 * bf2f((unsigned short)c[e]) +
              w11 * bf2f((unsigned short)d[e]);
    pk[e] = (unsigned short)f2bf(v);
  }
  *(u16x8*)((char*)wt + ((size_t)(b * HH + y) * PW + x + 4) * (CC * 2) +
            cw * 16) = pk;
}

// ---------------- Kernel 1 (fallback): gather f32 planes directly -----------
__global__ __launch_bounds__(256) void warp_fallback(
    const float* __restrict__ two, const float* __restrict__ flow,
    __hip_bfloat16* __restrict__ wt) {
  int idx = blockIdx.x * 256 + threadIdx.x;
  if (idx >= BB * HWSZ) return;
  int x = idx % WW;
  int y = (idx / WW) % HH;
  int b = idx / HWSZ;

  float fx = flow[(b * 2 + 0) * HWSZ + y * WW + x] * 2.5f;
  float fy = flow[(b * 2 + 1) * HWSZ + y * WW + x] * 2.5f;
  float px = (float)x + fx;
  float py = (float)y + fy;
  float x0f = floorf(px), y0f = floorf(py);
  int x0 = (int)x0f, y0 = (int)y0f;
  int x1 = x0 + 1, y1 = y0 + 1;
  float wx1 = px - x0f, wx0 = 1.0f - wx1;
  float wy1 = py - y0f, wy0 = 1.0f - wy1;
  bool vx0 = (x0 >= 0) && (x0 < WW);
  bool vx1 = (x1 >= 0) && (x1 < WW);
  bool vy0 = (y0 >= 0) && (y0 < HH);
  bool vy1 = (y1 >= 0) && (y1 < HH);
  float w00 = (vx0 && vy0) ? wx0 * wy0 : 0.0f;
  float w01 = (vx1 && vy0) ? wx1 * wy0 : 0.0f;
  float w10 = (vx0 && vy1) ? wx0 * wy1 : 0.0f;
  float w11 = (vx1 && vy1) ? wx1 * wy1 : 0.0f;
  int cx0 = min(max(x0, 0), WW - 1);
  int cx1 = min(max(x1, 0), WW - 1);
  int cy0 = min(max(y0, 0), HH - 1);
  int cy1 = min(max(y1, 0), HH - 1);
  int o00 = cy0 * WW + cx0;
  int o01 = cy0 * WW + cx1;
  int o10 = cy1 * WW + cx0;
  int o11 = cy1 * WW + cx1;

  const float* p = two + (size_t)b * CC * HWSZ;
  char* wo = (char*)wt + ((size_t)((size_t)(b * HH + y) * PW) + x + 4) * CC * 2;
#pragma unroll 4
  for (int j = 0; j < 16; ++j) {
    u16x8 pk;
#pragma unroll
    for (int jj = 0; jj < 8; ++jj) {
      int c = j * 8 + jj;
      const float* pc = p + (size_t)c * HWSZ;
      float v = w00 * pc[o00] + w01 * pc[o01] + w10 * pc[o10] + w11 * pc[o11];
      pk[jj] = (unsigned short)f2bf(v);
    }
    *(u16x8*)(wo + j * 16) = pk;
  }
}

// ---------------- Kernel 2: correlation, overlapped half-staged MFMA --------
// R16 C-split through TWO 39.4KB half-buffers (78.8KB). Issue order
// {h0-gloads, A-loads, h1-gloads}: in-order vmcnt retirement means the
// compiler's A-register waits imply h0 completion while h1's loads stay in
// flight across a RAW s_barrier; h1 staging hides under compute-h0.
#define YTB 8
#define NROWS 14                 // YTB + 6
#define NPOS 22
#define HROWCH (NPOS * 8)        // 176 16B-chunks per row (64-ch half)
#define HCHUNKS (NROWS * HROWCH) // 2464 chunks = 39,424 B
#define HBYTES (HCHUNKS * 16)

__global__ __launch_bounds__(512, 4) void corr_kernel(
    const float* __restrict__ one, const __hip_bfloat16* __restrict__ wt,
    float* __restrict__ out) {
  __shared__ uint4 ldsb[2][HCHUNKS];  // 78,848 B

  int bid = blockIdx.x;                    // 1792 = 8 * 224
  int wg = (bid & 7) * 224 + (bid >> 3);   // XCD-chunked, bijective
  int b = wg / 896;
  int rem = wg - b * 896;
  int xt = rem >> 5;   // 0..27
  int yt = rem & 31;   // 0..31
  int ybase = yt * YTB;
  int X0 = xt * 16;
  int tid = threadIdx.x;
  int w = tid >> 6;   // wave 0..7
  int l = tid & 63;
  int lp = l & 15;
  int lg = l >> 4;
  int y = ybase + w;

  const char* wbase =
      (const char*)wt + (((size_t)(b * HH)) * PW + X0 + 1) * (CC * 2);
  bool interior = (ybase >= 3) && (ybase + NROWS - 3 <= HH);

// Interior async stage of half H into buffer BUF (linear dest, pre-swizzled
// source cw ^= p&7).
#define STAGE_HALF_G(H, BUF)                                                  \
  _Pragma("unroll") for (int k = 0; k < 5; ++k) {                             \
    int ci = tid + k * 512;                                                   \
    if (ci < HCHUNKS) {                                                       \
      int row = ci / HROWCH;                                                  \
      int r2 = ci - row * HROWCH;                                             \
      int p = r2 >> 3;                                                        \
      int cw = r2 & 7;                                                        \
      int yy = ybase - 3 + row;                                               \
      const char* g = wbase + (size_t)yy * (PW * CC * 2) + p * 256 +          \
                      (H)*128 + (cw ^ (p & 7)) * 16;                          \
      gload_lds16(g, (char*)ldsb + (BUF)*HBYTES +                             \
                         (size_t)(k * 512 + (tid & ~63)) * 16);               \
    }                                                                         \
  }

// Edge reg-staged variant with zero fill (swizzled ds_write, same placement).
#define STAGE_HALF_E(H, BUF)                                                  \
  _Pragma("unroll") for (int k = 0; k < 5; ++k) {                             \
    int ci = tid + k * 512;                                                   \
    if (ci < HCHUNKS) {                                                       \
      int row = ci / HROWCH;                                                  \
      int r2 = ci - row * HROWCH;                                             \
      int p = r2 >> 3;                                                        \
      int cw = r2 & 7;                                                        \
      int yy = ybase - 3 + row;                                               \
      uint4 v = {0, 0, 0, 0};                                                 \
      if (yy >= 0 && yy < HH)                                                 \
        v = *(const uint4*)(wbase + (size_t)yy * (PW * CC * 2) + p * 256 +    \
                            (H)*128 + cw * 16);                               \
      *(uint4*)((char*)ldsb + (BUF)*HBYTES + ((ci * 16) ^ ((p & 7) << 4))) =  \
          v;                                                                  \
    }                                                                         \
  }

#define COMPUTE_HALF(BUF, T0)                                                 \
  _Pragma("unroll") for (int dj = 0; dj < 7; ++dj) {                          \
    int rl = w + dj;                                                          \
    int b0 = (rl * NPOS + lp) << 7;                                           \
    int b1 = (rl * NPOS + p1) << 7;                                           \
    _Pragma("unroll") for (int tl = 0; tl < 2; ++tl) {                        \
      bf16x8 v0 = *(const bf16x8*)((const char*)ldsb + (BUF)*HBYTES +         \
                                   (b0 + cs0[tl]));                           \
      bf16x8 v1 = *(const bf16x8*)((const char*)ldsb + (BUF)*HBYTES +         \
                                   (b1 + cs1[tl]));                           \
      acc[dj][0] = __builtin_amdgcn_mfma_f32_16x16x32_bf16(                   \
          afr[(T0) + tl], v0, acc[dj][0], 0, 0, 0);                           \
      acc[dj][1] = __builtin_amdgcn_mfma_f32_16x16x32_bf16(                   \
          afr[(T0) + tl], v1, acc[dj][1], 0, 0, 0);                           \
    }                                                                         \
  }

  const float* Abase = one + ((size_t)(b * CC) * HH + y) * WW + X0 + lp;
  bf16x8 afr[4];
  int p1 = (lp + 16 < 21) ? (lp + 16) : 21;
  int cs0[2], cs1[2];
#pragma unroll
  for (int tl = 0; tl < 2; ++tl) {
    cs0[tl] = ((tl * 4 + lg) ^ (lp & 7)) << 4;
    cs1[tl] = ((tl * 4 + lg) ^ (p1 & 7)) << 4;
  }
  f32x4 acc[7][2] = {};

  if (interior) {
    // issue order matters: h0 gloads (oldest) -> A loads -> h1 gloads.
    STAGE_HALF_G(0, 0)
    __builtin_amdgcn_sched_barrier(0);
#pragma unroll
    for (int t = 0; t < 4; ++t)
#pragma unroll
      for (int j = 0; j < 8; ++j)
        afr[t][j] = f2bf(Abase[(size_t)(t * 32 + lg * 8 + j) * HWSZ]);
    __builtin_amdgcn_sched_barrier(0);
    STAGE_HALF_G(1, 1)
    __builtin_amdgcn_sched_barrier(0);
    // A-register waits (compiler-inserted) retire h0's older loads too;
    // h1's 5 loads/wave stay in flight across this RAW barrier.
    __builtin_amdgcn_s_barrier();  // B1: h0 staged (h1 still streaming)
    __builtin_amdgcn_sched_barrier(0);

    COMPUTE_HALF(0, 0)

    asm volatile("s_waitcnt vmcnt(0)" ::: "memory");
    __builtin_amdgcn_sched_barrier(0);
    __builtin_amdgcn_s_barrier();  // B2: h1 staged; all waves past h0 compute
    __builtin_amdgcn_sched_barrier(0);

    COMPUTE_HALF(1, 2)
    // sc-write below overwrites buf0: safe, all buf0 reads done at B2.
  } else {
    STAGE_HALF_E(0, 0)
    STAGE_HALF_E(1, 1)
#pragma unroll
    for (int t = 0; t < 4; ++t)
#pragma unroll
      for (int j = 0; j < 8; ++j)
        afr[t][j] = f2bf(Abase[(size_t)(t * 32 + lg * 8 + j) * HWSZ]);
    __syncthreads();
    COMPUTE_HALF(0, 0)
    COMPUTE_HALF(1, 2)
    __syncthreads();  // all buf0 reads done before sc overwrite
  }

  // ---- Epilogue: LDS transpose (in buf0) -> dense stores ------------------
  // D layout: col = lane&15 (+16*nt) = pos, row = 4*(lane>>4)+reg = x_local.
  float* sc = (float*)ldsb;  // [49][8][16] f32, col-swizzled by +k (mod 16)
#pragma unroll
  for (int dj = 0; dj < 7; ++dj) {
#pragma unroll
    for (int nt = 0; nt < 2; ++nt) {
      int post = lp + 16 * nt;
#pragma unroll
      for (int r = 0; r < 4; ++r) {
        int xlc = 4 * lg + r;
        int di = post - xlc;
        if (di >= 0 && di <= 6) {
          int k = dj * 7 + di;
          sc[k * 128 + w * 16 + ((xlc + k) & 15)] = acc[dj][nt][r];
        }
      }
    }
  }
  __syncthreads();  // sc written

  float* ob = out + (size_t)(b * KK) * HWSZ + (size_t)ybase * WW + X0;
#pragma unroll
  for (int i = 0; i < 13; ++i) {
    int e = tid + i * 512;
    if (e < KK * 128) {
      int k = e >> 7;
      int yr = (e >> 4) & 7;
      int px = e & 15;
      float v = sc[k * 128 + yr * 16 + ((px + k) & 15)] * (1.0f / 128.0f);
      v = (v > 0.0f) ? v : 0.1f * v;
      ob[(size_t)k * HWSZ + yr * WW + px] = v;
    }
  }
#undef STAGE_HALF_G
#undef STAGE_HALF_E
#undef COMPUTE_HALF
}

// ---------------- launch ----------------------------------------------------
extern "C" void kernel_launch(void* const* d_in, const int* in_sizes, int n_in,
                              void* d_out, int out_size, void* d_ws,
                              size_t ws_size, hipStream_t stream) {
  const float* tenOne = (const float*)d_in[0];
  const float* tenTwo = (const float*)d_in[1];
  const float* tenFlow = (const float*)d_in[2];

  __hip_bfloat16* wt = (__hip_bfloat16*)d_ws;

  if (ws_size >= WS_NEED) {
    __hip_bfloat16* two_t = (__hip_bfloat16*)((char*)d_ws + WT_BYTES);
    transpose_kernel<<<BB * (HWSZ / 32), 256, 0, stream>>>(tenTwo, two_t, wt);
    warp_fast<<<3584, 1024, 0, stream>>>(two_t, tenFlow, wt);
  } else {
    border_kernel<<<256, 256, 0, stream>>>(wt);
    int blocks = (BB * HWSZ + 255) / 256;
    warp_fallback<<<blocks, 256, 0, stream>>>(tenTwo, tenFlow, wt);
  }
  corr_kernel<<<1792, 512, 0, stream>>>(tenOne, wt, (float*)d_out);
}

// Round 19
// 114.836 us; speedup vs baseline: 1.1737x; 1.1422x over previous
//
#include <hip/hip_runtime.h>
#include <hip/hip_bf16.h>

// Shapes fixed by setup_inputs(): B=2, C=128, H=256, W=448, stride=1.
#define BB 2
#define CC 128
#define HH 256
#define WW 448
#define KK 49
#define HWSZ (HH * WW)

#define TWT_BYTES ((size_t)BB * HH * WW * CC * 2)  // 58,720,256

typedef __attribute__((ext_vector_type(8))) short bf16x8;
typedef __attribute__((ext_vector_type(4))) float f32x4;
typedef __attribute__((ext_vector_type(8))) unsigned short u16x8;

static __device__ __forceinline__ short f2bf(float v) {
  __hip_bfloat16 h = __float2bfloat16(v);
  return *reinterpret_cast<short*>(&h);
}
static __device__ __forceinline__ float bf2f(unsigned short u) {
  unsigned int x = ((unsigned int)u) << 16;
  return __uint_as_float(x);
}

// ---------------- Kernel T: transpose tenTwo [c][p] f32 -> two_t [p][c] bf16
__global__ __launch_bounds__(256) void transpose_kernel(
    const float* __restrict__ two, __hip_bfloat16* __restrict__ two_t) {
  __shared__ float lds[128 * 33];
  int bid = blockIdx.x;  // BB * 3584 = 7168
  int b = bid / (HWSZ / 32);
  int tile = bid - b * (HWSZ / 32);
  int P0 = tile * 32;

  const float* src = two + (size_t)b * CC * HWSZ + P0;
  int t = threadIdx.x;
  int bc = t >> 3;  // 0..31
  int f = t & 7;    // 0..7
#pragma unroll
  for (int k = 0; k < 4; ++k) {
    int c = bc + k * 32;
    float4 v = *(const float4*)(src + (size_t)c * HWSZ + f * 4);
    float* d = &lds[c * 33 + f * 4];
    d[0] = v.x; d[1] = v.y; d[2] = v.z; d[3] = v.w;
  }
  __syncthreads();

  int q = t & 7;    // c-chunk of 16
  int pl = t >> 3;  // 0..31 pixel
  int cs = q * 16;
  u16x8 pk0, pk1;
#pragma unroll
  for (int j = 0; j < 8; ++j)
    pk0[j] = (unsigned short)f2bf(lds[(cs + j) * 33 + pl]);
#pragma unroll
  for (int j = 0; j < 8; ++j)
    pk1[j] = (unsigned short)f2bf(lds[(cs + 8 + j) * 33 + pl]);
  char* dst = (char*)two_t + ((size_t)((size_t)b * HWSZ + P0 + pl) * CC + cs) * 2;
  *(u16x8*)dst = pk0;
  *(u16x8*)(dst + 16) = pk1;
}

// ---------------- Kernel 2: FUSED backwarp + correlation via MFMA -----------
// R14 tiling/compute/epilogue (bench-verified), but staging GATHERS the
// warped tile directly from two_t using flow: per chunk (row,pos,cw16),
// 16 lanes share one warped pixel -> flow read is lane-uniform, 4 corner
// reads are 256B dense per corner, blend in f32, ds_write with the 4-bit
// XOR swizzle. The wt intermediate (60MB write + 150MB read + one kernel)
// is gone; two_t (59MB) is L3-resident for the re-gather.
#define YTB 8
#define NROWS 14               // YTB + 6
#define NPOS 22
#define ROWCH (NPOS * 16)      // 352 16B-chunks per row
#define CHUNKS (NROWS * ROWCH) // 4928 chunks = 78,848 B

__global__ __launch_bounds__(512, 2) void corr_fused(
    const float* __restrict__ one, const __hip_bfloat16* __restrict__ two_t,
    const float* __restrict__ flow, float* __restrict__ out) {
  __shared__ uint4 ldsb[CHUNKS];

  int bid = blockIdx.x;                    // 1792 = 8 * 224
  int wg = (bid & 7) * 224 + (bid >> 3);   // XCD-chunked, bijective
  int b = wg / 896;
  int rem = wg - b * 896;
  int xt = rem >> 5;   // 0..27
  int yt = rem & 31;   // 0..31
  int ybase = yt * YTB;
  int X0 = xt * 16;
  int tid = threadIdx.x;
  int w = tid >> 6;   // wave 0..7
  int l = tid & 63;
  int lp = l & 15;
  int lg = l >> 4;
  int y = ybase + w;

  const char* tb = (const char*)two_t + (size_t)b * HWSZ * (CC * 2);
  const float* fxp = flow + (size_t)(b * 2 + 0) * HWSZ;
  const float* fyp = flow + (size_t)(b * 2 + 1) * HWSZ;

  // ---- fused gather-staging: warp the B tile straight into LDS ------------
#pragma unroll
  for (int k = 0; k < 10; ++k) {
    int ci = tid + k * 512;
    if (ci < CHUNKS) {
      int row = ci / ROWCH;
      int r2 = ci - row * ROWCH;
      int p = r2 >> 4;   // pos 0..21
      int cw = r2 & 15;  // 16B channel chunk
      int yy = ybase - 3 + row;   // warped-source row
      int x = X0 + p - 3;         // warped-source col
      bool vpix = (yy >= 0) && (yy < HH) && (x >= 0) && (x < WW);
      int yyc = min(max(yy, 0), HH - 1);
      int xc = min(max(x, 0), WW - 1);
      float fx = fxp[yyc * WW + xc] * 2.5f;  // lane-uniform per 16 lanes
      float fy = fyp[yyc * WW + xc] * 2.5f;
      float pxf = (float)x + fx;
      float pyf = (float)yy + fy;
      float x0f = floorf(pxf), y0f = floorf(pyf);
      int x0 = (int)x0f, y0 = (int)y0f;
      int x1 = x0 + 1, y1 = y0 + 1;
      float wx1 = pxf - x0f, wx0 = 1.0f - wx1;
      float wy1 = pyf - y0f, wy0 = 1.0f - wy1;
      float gate = vpix ? 1.0f : 0.0f;
      wy0 *= gate;
      wy1 *= gate;
      bool vx0 = (x0 >= 0) && (x0 < WW);
      bool vx1 = (x1 >= 0) && (x1 < WW);
      bool vy0 = (y0 >= 0) && (y0 < HH);
      bool vy1 = (y1 >= 0) && (y1 < HH);
      float w00 = (vx0 && vy0) ? wx0 * wy0 : 0.0f;
      float w01 = (vx1 && vy0) ? wx1 * wy0 : 0.0f;
      float w10 = (vx0 && vy1) ? wx0 * wy1 : 0.0f;
      float w11 = (vx1 && vy1) ? wx1 * wy1 : 0.0f;
      int cx0 = min(max(x0, 0), WW - 1);
      int cx1 = min(max(x1, 0), WW - 1);
      int cy0 = min(max(y0, 0), HH - 1);
      int cy1 = min(max(y1, 0), HH - 1);

      u16x8 ca = *(const u16x8*)(tb + ((size_t)cy0 * WW + cx0) * 256 + cw * 16);
      u16x8 cb = *(const u16x8*)(tb + ((size_t)cy0 * WW + cx1) * 256 + cw * 16);
      u16x8 cc = *(const u16x8*)(tb + ((size_t)cy1 * WW + cx0) * 256 + cw * 16);
      u16x8 cd = *(const u16x8*)(tb + ((size_t)cy1 * WW + cx1) * 256 + cw * 16);

      u16x8 pk;
#pragma unroll
      for (int e = 0; e < 8; ++e) {
        float v = w00 * bf2f((unsigned short)ca[e]) +
                  w01 * bf2f((unsigned short)cb[e]) +
                  w10 * bf2f((unsigned short)cc[e]) +
                  w11 * bf2f((unsigned short)cd[e]);
        pk[e] = (unsigned short)f2bf(v);
      }
      *(u16x8*)((char*)ldsb + ((ci * 16) ^ ((p & 15) << 4))) = pk;
    }
  }

  // ---- A fragments ---------------------------------------------------------
  const float* Abase = one + ((size_t)(b * CC) * HH + y) * WW + X0 + lp;
  bf16x8 afr[4];
#pragma unroll
  for (int t = 0; t < 4; ++t)
#pragma unroll
    for (int j = 0; j < 8; ++j)
      afr[t][j] = f2bf(Abase[(size_t)(t * 32 + lg * 8 + j) * HWSZ]);

  __syncthreads();  // staged tile visible

  // ---- compute: pure ds_read_b128 + MFMA (R14 verbatim) -------------------
  int p1 = (lp + 16 < 21) ? (lp + 16) : 21;
  int cosw0[4], cosw1[4];
#pragma unroll
  for (int t = 0; t < 4; ++t) {
    int co = t * 64 + lg * 16;
    cosw0[t] = co ^ ((lp & 15) << 4);
    cosw1[t] = co ^ ((p1 & 15) << 4);
  }

  f32x4 acc[7][2] = {};
#pragma unroll
  for (int dj = 0; dj < 7; ++dj) {
    int rl = w + dj;  // LDS row for yy = y + dj - 3
    int b0 = (rl * NPOS + lp) << 8;
    int b1 = (rl * NPOS + p1) << 8;
#pragma unroll
    for (int t = 0; t < 4; ++t) {
      bf16x8 v0 = *(const bf16x8*)((const char*)ldsb + (b0 + cosw0[t]));
      bf16x8 v1 = *(const bf16x8*)((const char*)ldsb + (b1 + cosw1[t]));
      acc[dj][0] = __builtin_amdgcn_mfma_f32_16x16x32_bf16(afr[t], v0,
                                                           acc[dj][0], 0, 0, 0);
      acc[dj][1] = __builtin_amdgcn_mfma_f32_16x16x32_bf16(afr[t], v1,
                                                           acc[dj][1], 0, 0, 0);
    }
  }

  // ---- Epilogue: LDS transpose -> dense stores (R14 verbatim) -------------
  // D layout: col = lane&15 (+16*nt) = pos, row = 4*(lane>>4)+reg = x_local.
  __syncthreads();  // all ds_reads of ldsb done; safe to reuse as scratch
  float* sc = (float*)ldsb;  // [49][8][16] f32, col-swizzled by +k (mod 16)
#pragma unroll
  for (int dj = 0; dj < 7; ++dj) {
#pragma unroll
    for (int nt = 0; nt < 2; ++nt) {
      int post = lp + 16 * nt;
#pragma unroll
      for (int r = 0; r < 4; ++r) {
        int xlc = 4 * lg + r;
        int di = post - xlc;
        if (di >= 0 && di <= 6) {
          int k = dj * 7 + di;
          sc[k * 128 + w * 16 + ((xlc + k) & 15)] = acc[dj][nt][r];
        }
      }
    }
  }
  __syncthreads();

  float* ob = out + (size_t)(b * KK) * HWSZ + (size_t)ybase * WW + X0;
#pragma unroll
  for (int i = 0; i < 13; ++i) {
    int e = tid + i * 512;
    if (e < KK * 128) {
      int k = e >> 7;
      int yr = (e >> 4) & 7;
      int px = e & 15;
      float v = sc[k * 128 + yr * 16 + ((px + k) & 15)] * (1.0f / 128.0f);
      v = (v > 0.0f) ? v : 0.1f * v;
      ob[(size_t)k * HWSZ + yr * WW + px] = v;
    }
  }
}

// ---------------- launch ----------------------------------------------------
extern "C" void kernel_launch(void* const* d_in, const int* in_sizes, int n_in,
                              void* d_out, int out_size, void* d_ws,
                              size_t ws_size, hipStream_t stream) {
  const float* tenOne = (const float*)d_in[0];
  const float* tenTwo = (const float*)d_in[1];
  const float* tenFlow = (const float*)d_in[2];

  __hip_bfloat16* two_t = (__hip_bfloat16*)d_ws;  // 58.7 MB (ws is larger)

  transpose_kernel<<<BB * (HWSZ / 32), 256, 0, stream>>>(tenTwo, two_t);
  corr_fused<<<1792, 512, 0, stream>>>(tenOne, two_t, tenFlow,
                                       (float*)d_out);
}